// Round 1
// baseline (378.646 us; speedup 1.0000x reference)
//
#include <hip/hip_runtime.h>
#include <hip/hip_bf16.h>

#define NN 8192
#define ND 128
#define BSZ 4096
#define CTX1 32
#define SRC 4096
#define TOPK 8
#define DROPC 5

using f4 = __attribute__((ext_vector_type(4))) float;
using bfrag = __attribute__((ext_vector_type(8))) short;

__device__ __forceinline__ short f2bf(float x) {
  __hip_bfloat16 h = __float2bfloat16(x);
  return __builtin_bit_cast(short, h);
}

// ---------------- prep: tfn (normalized trainfeature[:, :64]), wsum, meanpara ----
__global__ __launch_bounds__(256) void prep_kernel(
    const float* __restrict__ trainfeature, const float* __restrict__ bsnf,
    const float* __restrict__ para, float* __restrict__ tfn,
    float* __restrict__ wsum, float* __restrict__ meanpara) {
  int blk = blockIdx.x;
  int t = threadIdx.x;
  if (blk < 2048) {                      // tfn: 4 rows per block, one wave per row
    int row = blk * 4 + (t >> 6);
    int j = t & 63;
    float x = trainfeature[(size_t)row * ND + j];
    float ss = x * x;
    #pragma unroll
    for (int o = 32; o > 0; o >>= 1) ss += __shfl_xor(ss, o);
    float nrm = sqrtf(ss) + 1e-8f;
    tfn[(size_t)row * 64 + j] = x / nrm;
  } else if (blk < 4096) {               // wsum: 2 rows per block
    int b = (blk - 2048) * 2 + (t >> 7);
    int k = t & 127;
    float s = 0.f;
    #pragma unroll
    for (int tt = 0; tt < TOPK; ++tt)
      s += para[tt] * bsnf[((size_t)b * TOPK + tt) * ND + k];
    wsum[(size_t)b * ND + k] = s * (1.0f / TOPK);
  } else {
    if (t == 0) {
      float s = 0.f;
      for (int tt = 0; tt < TOPK; ++tt) s += para[tt];
      *meanpara = s * (1.0f / TOPK);
    }
  }
}

// ---------------- generic f32 GEMM: C[M][128] = A[M][128] @ W[128][128] (+ bscale*bias)
// optional f32 output Cf, optional transposed bf16 output CtB[128][M]
__global__ __launch_bounds__(256) void gemm128_kernel(
    const float* __restrict__ A, const float* __restrict__ W,
    const float* __restrict__ bias, const float* __restrict__ bscale_ptr,
    float* __restrict__ Cf, short* __restrict__ CtB, int M) {
  __shared__ float Ws[128][132];
  __shared__ float As[64][128];
  int t = threadIdx.x;
  for (int i = t; i < 128 * 32; i += 256) {
    int r = i >> 5, c = (i & 31) * 4;
    *(f4*)&Ws[r][c] = *(const f4*)&W[(size_t)r * 128 + c];
  }
  int row0 = blockIdx.x * 64;
  for (int i = t; i < 64 * 32; i += 256) {
    int r = i >> 5, c = (i & 31) * 4;
    *(f4*)&As[r][c] = *(const f4*)&A[(size_t)(row0 + r) * 128 + c];
  }
  __syncthreads();
  int tr = (t >> 5) * 8;
  int tc = (t & 31) * 4;
  float acc[8][4];
  #pragma unroll
  for (int i = 0; i < 8; i++)
    #pragma unroll
    for (int j = 0; j < 4; j++) acc[i][j] = 0.f;
  for (int k = 0; k < 128; k++) {
    f4 w = *(const f4*)&Ws[k][tc];
    #pragma unroll
    for (int i = 0; i < 8; i++) {
      float a = As[tr + i][k];
      acc[i][0] = fmaf(a, w[0], acc[i][0]);
      acc[i][1] = fmaf(a, w[1], acc[i][1]);
      acc[i][2] = fmaf(a, w[2], acc[i][2]);
      acc[i][3] = fmaf(a, w[3], acc[i][3]);
    }
  }
  float bsc = bscale_ptr ? *bscale_ptr : 1.0f;
  #pragma unroll
  for (int i = 0; i < 8; i++) {
    int r = row0 + tr + i;
    #pragma unroll
    for (int j = 0; j < 4; j++) {
      float v = acc[i][j];
      if (bias) v += bias[tc + j] * bsc;
      if (Cf) Cf[(size_t)r * 128 + tc + j] = v;
      if (CtB) CtB[(size_t)(tc + j) * M + r] = f2bf(v);
    }
  }
}

// ---------------- big GEMM: partial[g][split] = A_f32(8192x8192) @ X_bf16(8192x128)
__global__ __launch_bounds__(256) void big_gemm_kernel(
    const float* __restrict__ adj, const float* __restrict__ graphm,
    const short* __restrict__ XgT, const short* __restrict__ XET,
    float* __restrict__ partials, int ksplit, int kc) {
  const int g = blockIdx.z;
  const float* __restrict__ Am = g ? graphm : adj;
  const short* __restrict__ Xt = g ? XET : XgT;
  const int m0 = blockIdx.x * 128;
  const int split = blockIdx.y;
  const int t = threadIdx.x;
  const int lane = t & 63;
  const int wave = t >> 6;
  const int wr = (wave >> 1) * 64;
  const int wc = (wave & 1) * 64;
  const int fr = lane & 15;
  const int fk = (lane >> 4) * 8;

  __shared__ short As[128][40];   // stride 40 bf16 = 80B: breaks bank aliasing
  __shared__ short Bs[128][40];

  f4 acc[4][4];
  #pragma unroll
  for (int i = 0; i < 4; i++)
    #pragma unroll
    for (int j = 0; j < 4; j++) acc[i][j] = (f4){0.f, 0.f, 0.f, 0.f};

  const int ar = t >> 1;
  const int ak = (t & 1) * 16;
  const size_t arow = (size_t)(m0 + ar) * NN;
  const size_t brow = (size_t)ar * NN;
  const int kbeg = split * kc;

  for (int k0 = kbeg; k0 < kbeg + kc; k0 += 32) {
    const float* ap = Am + arow + k0 + ak;
    f4 v0 = *(const f4*)(ap);
    f4 v1 = *(const f4*)(ap + 4);
    f4 v2 = *(const f4*)(ap + 8);
    f4 v3 = *(const f4*)(ap + 12);
    const short* bp = Xt + brow + k0 + ak;
    bfrag b0 = *(const bfrag*)(bp);
    bfrag b1 = *(const bfrag*)(bp + 8);
    bfrag h0, h1;
    h0[0] = f2bf(v0[0]); h0[1] = f2bf(v0[1]); h0[2] = f2bf(v0[2]); h0[3] = f2bf(v0[3]);
    h0[4] = f2bf(v1[0]); h0[5] = f2bf(v1[1]); h0[6] = f2bf(v1[2]); h0[7] = f2bf(v1[3]);
    h1[0] = f2bf(v2[0]); h1[1] = f2bf(v2[1]); h1[2] = f2bf(v2[2]); h1[3] = f2bf(v2[3]);
    h1[4] = f2bf(v3[0]); h1[5] = f2bf(v3[1]); h1[6] = f2bf(v3[2]); h1[7] = f2bf(v3[3]);
    *(bfrag*)&As[ar][ak] = h0;
    *(bfrag*)&As[ar][ak + 8] = h1;
    *(bfrag*)&Bs[ar][ak] = b0;
    *(bfrag*)&Bs[ar][ak + 8] = b1;
    __syncthreads();
    bfrag a[4], bb[4];
    #pragma unroll
    for (int i = 0; i < 4; i++) a[i] = *(const bfrag*)&As[wr + i * 16 + fr][fk];
    #pragma unroll
    for (int j = 0; j < 4; j++) bb[j] = *(const bfrag*)&Bs[wc + j * 16 + fr][fk];
    #pragma unroll
    for (int i = 0; i < 4; i++)
      #pragma unroll
      for (int j = 0; j < 4; j++)
        acc[i][j] = __builtin_amdgcn_mfma_f32_16x16x32_bf16(a[i], bb[j], acc[i][j], 0, 0, 0);
    __syncthreads();
  }

  float* outp = partials + (((size_t)g * ksplit + split) * NN + m0) * 128;
  const int crow = (lane >> 4) * 4;
  #pragma unroll
  for (int i = 0; i < 4; i++)
    #pragma unroll
    for (int j = 0; j < 4; j++) {
      float* p = outp + (size_t)(wr + i * 16 + crow) * 128 + wc + j * 16 + fr;
      #pragma unroll
      for (int r = 0; r < 4; r++) p[(size_t)r * 128] = acc[i][j][r];
    }
}

// ---------------- reduce splits + bias + relu -> emb_g (g=0), emb_E (g=1)
__global__ __launch_bounds__(256) void reduce_kernel(
    const float* __restrict__ partials, const float* __restrict__ gcn_b,
    const float* __restrict__ gcnE_b, float* __restrict__ emb_g,
    float* __restrict__ emb_E, int ksplit) {
  int g = blockIdx.y;
  size_t i = ((size_t)blockIdx.x * 256 + threadIdx.x) * 4;
  const float* base = partials + (size_t)g * ksplit * NN * 128;
  f4 s = {0.f, 0.f, 0.f, 0.f};
  for (int sp = 0; sp < ksplit; ++sp)
    s += *(const f4*)(base + (size_t)sp * NN * 128 + i);
  const float* bias = g ? gcnE_b : gcn_b;
  f4 bv = *(const f4*)(bias + (i & 127));
  s += bv;
  s[0] = fmaxf(s[0], 0.f); s[1] = fmaxf(s[1], 0.f);
  s[2] = fmaxf(s[2], 0.f); s[3] = fmaxf(s[3], 0.f);
  float* outp = g ? emb_E : emb_g;
  *(f4*)(outp + i) = s;
}

// ---------------- fused attention + concat + final matmul ----------------
__global__ __launch_bounds__(128) void attn_kernel(
    const int* __restrict__ node_rd, const int* __restrict__ batch_node_idx,
    const float* __restrict__ Qa, const float* __restrict__ Ka,
    const float* __restrict__ Va, const float* __restrict__ tfn,
    const float* __restrict__ emb_g, const float* __restrict__ simi,
    const float* __restrict__ lin_W, const float* __restrict__ lin_b,
    float* __restrict__ outr) {
  int b = blockIdx.x;
  int t = threadIdx.x;
  __shared__ int idx[CTX1];
  __shared__ float tf0[64];
  __shared__ float qv[128];
  __shared__ float cosv[CTX1];
  __shared__ float sc[8][CTX1];
  __shared__ float femb[384];

  if (t < CTX1) idx[t] = node_rd[(size_t)b * CTX1 + t] + (t == 0 ? SRC : 0);
  __syncthreads();
  int i0 = idx[0];
  if (t < 64) tf0[t] = tfn[(size_t)i0 * 64 + t];
  qv[t] = Qa[(size_t)i0 * 128 + t];
  __syncthreads();

  {  // cos[c]: 4 lanes per context
    int c = t >> 2, q = t & 3;
    const float* tfc = tfn + (size_t)idx[c] * 64;
    float s = 0.f;
    #pragma unroll
    for (int j = 0; j < 16; j++) s += tf0[q + j * 4] * tfc[q + j * 4];
    s += __shfl_xor(s, 1);
    s += __shfl_xor(s, 2);
    if (q == 0) cosv[c] = s;
  }
  __syncthreads();

  // scores[h][c]
  for (int p = t; p < 256; p += 128) {
    int h = p >> 5, c = p & 31;
    const float* kp = Ka + (size_t)idx[c] * 128 + h * 16;
    float s = 0.f;
    #pragma unroll
    for (int d = 0; d < 16; d++) s += qv[h * 16 + d] * kp[d];
    sc[h][c] = s * 0.25f + cosv[c];
  }
  __syncthreads();

  {  // softmax over c, 16 lanes per head
    int h = t >> 4, l = t & 15;
    float s0 = sc[h][l], s1 = sc[h][l + 16];
    float m = fmaxf(s0, s1);
    #pragma unroll
    for (int o = 1; o < 16; o <<= 1) m = fmaxf(m, __shfl_xor(m, o));
    float e0 = expf(s0 - m), e1 = expf(s1 - m);
    float sum = e0 + e1;
    #pragma unroll
    for (int o = 1; o < 16; o <<= 1) sum += __shfl_xor(sum, o);
    float inv = 1.0f / sum;
    sc[h][l] = e0 * inv;
    sc[h][l + 16] = e1 * inv;
  }
  __syncthreads();

  {  // PV + elu
    int h = t >> 4, d = t & 15;
    float o = 0.f;
    #pragma unroll 4
    for (int c = 0; c < CTX1; c++)
      o += sc[h][c] * Va[(size_t)idx[c] * 128 + h * 16 + d];
    femb[128 + t] = (o > 0.f) ? o : expm1f(o);
  }
  int bn = batch_node_idx[b];
  femb[t] = emb_g[(size_t)bn * 128 + t];
  femb[256 + t] = simi[(size_t)b * 128 + t];
  __syncthreads();

  float accv = lin_b[t];
  #pragma unroll 8
  for (int j = 0; j < 384; j++) accv = fmaf(femb[j], lin_W[(size_t)j * 128 + t], accv);
  outr[(size_t)b * 128 + t] = accv;
}

// ---------------- loss ----------------
__global__ __launch_bounds__(256) void loss_kernel(
    const float* __restrict__ target, const float* __restrict__ result,
    float* __restrict__ out_loss) {
  int t = threadIdx.x;
  float s = 0.f;
  for (int b = t; b < BSZ; b += 256) {
    float d = target[(size_t)b * 128 + DROPC] - result[(size_t)b * 128 + DROPC];
    s += d * d;
  }
  #pragma unroll
  for (int o = 32; o > 0; o >>= 1) s += __shfl_xor(s, o);
  __shared__ float red[4];
  if ((t & 63) == 0) red[t >> 6] = s;
  __syncthreads();
  if (t == 0) out_loss[0] = (red[0] + red[1] + red[2] + red[3]) * (1.0f / BSZ);
}

extern "C" void kernel_launch(void* const* d_in, const int* in_sizes, int n_in,
                              void* d_out, int out_size, void* d_ws, size_t ws_size,
                              hipStream_t stream) {
  const float* adj = (const float*)d_in[0];
  const float* graphm = (const float*)d_in[1];
  const float* node_emb_gcn = (const float*)d_in[2];
  const float* trainfeature = (const float*)d_in[3];
  const float* target_emb = (const float*)d_in[4];
  const float* bsnf = (const float*)d_in[5];
  const int* batch_node_idx = (const int*)d_in[8];
  const int* node_rd = (const int*)d_in[9];
  const float* translate_W = (const float*)d_in[10];
  const float* translate_b = (const float*)d_in[11];
  const float* paraForCos = (const float*)d_in[12];
  const float* gcn_W = (const float*)d_in[13];
  const float* gcn_b = (const float*)d_in[14];
  const float* gcnE_W = (const float*)d_in[15];
  const float* gcnE_b = (const float*)d_in[16];
  const float* Wq = (const float*)d_in[17];
  const float* Wk = (const float*)d_in[18];
  const float* Wv = (const float*)d_in[19];
  const float* lin_W = (const float*)d_in[20];
  const float* lin_b = (const float*)d_in[21];

  char* ws = (char*)d_ws;
  size_t off = 0;
  auto alloc = [&](size_t bytes) {
    void* p = ws + off;
    off += (bytes + 255) & ~(size_t)255;
    return p;
  };
  short* XgT = (short*)alloc((size_t)128 * NN * 2);
  short* XET = (short*)alloc((size_t)128 * NN * 2);
  float* tfn = (float*)alloc((size_t)NN * 64 * 4);
  float* wsum = (float*)alloc((size_t)BSZ * 128 * 4);
  float* simi = (float*)alloc((size_t)BSZ * 128 * 4);
  float* Qa = (float*)alloc((size_t)NN * 128 * 4);
  float* Ka = (float*)alloc((size_t)NN * 128 * 4);
  float* Va = (float*)alloc((size_t)NN * 128 * 4);
  float* emb_g = (float*)alloc((size_t)NN * 128 * 4);
  float* emb_E = (float*)alloc((size_t)NN * 128 * 4);
  float* meanpara = (float*)alloc(256);

  size_t per_split = 2ull * NN * 128 * 4;  // both gemms, one split = 8MB
  int ksplit = 1;
  if (off + 8 * per_split <= ws_size) ksplit = 8;
  else if (off + 4 * per_split <= ws_size) ksplit = 4;
  else if (off + 2 * per_split <= ws_size) ksplit = 2;
  float* partials = (float*)(ws + off);
  int kc = NN / ksplit;

  float* out_res = (float*)d_out;
  float* out_loss = out_res + (size_t)BSZ * 128;

  prep_kernel<<<4097, 256, 0, stream>>>(trainfeature, bsnf, paraForCos, tfn, wsum, meanpara);
  gemm128_kernel<<<NN / 64, 256, 0, stream>>>(node_emb_gcn, gcn_W, nullptr, nullptr,
                                              nullptr, XgT, NN);
  gemm128_kernel<<<NN / 64, 256, 0, stream>>>(trainfeature, gcnE_W, nullptr, nullptr,
                                              nullptr, XET, NN);
  big_gemm_kernel<<<dim3(NN / 128, ksplit, 2), 256, 0, stream>>>(adj, graphm, XgT, XET,
                                                                 partials, ksplit, kc);
  reduce_kernel<<<dim3(NN * 128 / (256 * 4), 2), 256, 0, stream>>>(partials, gcn_b, gcnE_b,
                                                                   emb_g, emb_E, ksplit);
  gemm128_kernel<<<NN / 64, 256, 0, stream>>>(emb_E, Wq, nullptr, nullptr, Qa, nullptr, NN);
  gemm128_kernel<<<NN / 64, 256, 0, stream>>>(emb_E, Wk, nullptr, nullptr, Ka, nullptr, NN);
  gemm128_kernel<<<NN / 64, 256, 0, stream>>>(emb_E, Wv, nullptr, nullptr, Va, nullptr, NN);
  gemm128_kernel<<<BSZ / 64, 256, 0, stream>>>(wsum, translate_W, translate_b, meanpara,
                                               simi, nullptr, BSZ);
  attn_kernel<<<BSZ, 128, 0, stream>>>(node_rd, batch_node_idx, Qa, Ka, Va, tfn, emb_g,
                                       simi, lin_W, lin_b, out_res);
  loss_kernel<<<1, 256, 0, stream>>>(target_emb, out_res, out_loss);
}

// Round 2
// 333.088 us; speedup vs baseline: 1.1368x; 1.1368x over previous
//
#include <hip/hip_runtime.h>
#include <hip/hip_bf16.h>

#define NN 8192
#define ND 128
#define BSZ 4096
#define CTX1 32
#define SRC 4096
#define TOPK 8
#define DROPC 5

using f4 = __attribute__((ext_vector_type(4))) float;
using bfrag = __attribute__((ext_vector_type(8))) short;

__device__ __forceinline__ short f2bf(float x) {
  __hip_bfloat16 h = __float2bfloat16(x);
  return __builtin_bit_cast(short, h);
}

// ---------------- prep: tfn (normalized trainfeature[:, :64]), wsum, meanpara ----
__global__ __launch_bounds__(256) void prep_kernel(
    const float* __restrict__ trainfeature, const float* __restrict__ bsnf,
    const float* __restrict__ para, float* __restrict__ tfn,
    float* __restrict__ wsum, float* __restrict__ meanpara) {
  int blk = blockIdx.x;
  int t = threadIdx.x;
  if (blk < 2048) {                      // tfn: 4 rows per block, one wave per row
    int row = blk * 4 + (t >> 6);
    int j = t & 63;
    float x = trainfeature[(size_t)row * ND + j];
    float ss = x * x;
    #pragma unroll
    for (int o = 32; o > 0; o >>= 1) ss += __shfl_xor(ss, o);
    float nrm = sqrtf(ss) + 1e-8f;
    tfn[(size_t)row * 64 + j] = x / nrm;
  } else if (blk < 4096) {               // wsum: 2 rows per block
    int b = (blk - 2048) * 2 + (t >> 7);
    int k = t & 127;
    float s = 0.f;
    #pragma unroll
    for (int tt = 0; tt < TOPK; ++tt)
      s += para[tt] * bsnf[((size_t)b * TOPK + tt) * ND + k];
    wsum[(size_t)b * ND + k] = s * (1.0f / TOPK);
  } else {
    if (t == 0) {
      float s = 0.f;
      for (int tt = 0; tt < TOPK; ++tt) s += para[tt];
      *meanpara = s * (1.0f / TOPK);
    }
  }
}

// ---------------- generic f32 GEMM body: C[M][128] = A[M][128] @ W[128][128]
__device__ __forceinline__ void gemm128_body(
    const float* __restrict__ A, const float* __restrict__ W,
    const float* __restrict__ bias, const float* __restrict__ bscale_ptr,
    float* __restrict__ Cf, short* __restrict__ CtB, int M, int row0) {
  __shared__ float Ws[128][132];
  __shared__ float As[64][128];
  int t = threadIdx.x;
  for (int i = t; i < 128 * 32; i += 256) {
    int r = i >> 5, c = (i & 31) * 4;
    *(f4*)&Ws[r][c] = *(const f4*)&W[(size_t)r * 128 + c];
  }
  for (int i = t; i < 64 * 32; i += 256) {
    int r = i >> 5, c = (i & 31) * 4;
    *(f4*)&As[r][c] = *(const f4*)&A[(size_t)(row0 + r) * 128 + c];
  }
  __syncthreads();
  int tr = (t >> 5) * 8;
  int tc = (t & 31) * 4;
  float acc[8][4];
  #pragma unroll
  for (int i = 0; i < 8; i++)
    #pragma unroll
    for (int j = 0; j < 4; j++) acc[i][j] = 0.f;
  for (int k = 0; k < 128; k++) {
    f4 w = *(const f4*)&Ws[k][tc];
    #pragma unroll
    for (int i = 0; i < 8; i++) {
      float a = As[tr + i][k];
      acc[i][0] = fmaf(a, w[0], acc[i][0]);
      acc[i][1] = fmaf(a, w[1], acc[i][1]);
      acc[i][2] = fmaf(a, w[2], acc[i][2]);
      acc[i][3] = fmaf(a, w[3], acc[i][3]);
    }
  }
  float bsc = bscale_ptr ? *bscale_ptr : 1.0f;
  #pragma unroll
  for (int i = 0; i < 8; i++) {
    int r = row0 + tr + i;
    #pragma unroll
    for (int j = 0; j < 4; j++) {
      float v = acc[i][j];
      if (bias) v += bias[tc + j] * bsc;
      if (Cf) Cf[(size_t)r * 128 + tc + j] = v;
      if (CtB) CtB[(size_t)(tc + j) * M + r] = f2bf(v);
    }
  }
}

__global__ __launch_bounds__(256) void gemm128_kernel(
    const float* __restrict__ A, const float* __restrict__ W,
    const float* __restrict__ bias, const float* __restrict__ bscale_ptr,
    float* __restrict__ Cf, short* __restrict__ CtB, int M) {
  gemm128_body(A, W, bias, bscale_ptr, Cf, CtB, M, blockIdx.x * 64);
}

// 2 projections in one launch: y=0: A0@W0 -> T0 (bf16^T), y=1: A1@W1 -> T1
__global__ __launch_bounds__(256) void proj2_kernel(
    const float* __restrict__ A0, const float* __restrict__ W0, short* __restrict__ T0,
    const float* __restrict__ A1, const float* __restrict__ W1, short* __restrict__ T1) {
  if (blockIdx.y == 0)
    gemm128_body(A0, W0, nullptr, nullptr, nullptr, T0, NN, blockIdx.x * 64);
  else
    gemm128_body(A1, W1, nullptr, nullptr, nullptr, T1, NN, blockIdx.x * 64);
}

// QKV in one launch
__global__ __launch_bounds__(256) void qkv_kernel(
    const float* __restrict__ A, const float* __restrict__ Wq,
    const float* __restrict__ Wk, const float* __restrict__ Wv,
    float* __restrict__ Qa, float* __restrict__ Ka, float* __restrict__ Va) {
  const float* W = blockIdx.y == 0 ? Wq : (blockIdx.y == 1 ? Wk : Wv);
  float* C = blockIdx.y == 0 ? Qa : (blockIdx.y == 1 ? Ka : Va);
  gemm128_body(A, W, nullptr, nullptr, C, nullptr, NN, blockIdx.x * 64);
}

// ---------------- big GEMM: partial[g][split] = A_f32(8192x8192) @ X_bf16(8192x128)
// Register-staged prefetch: loads for K-step i+1 are issued right after the
// post-ds_write barrier, so they stay in flight across the MFMA phase.
__global__ __launch_bounds__(256, 3) void big_gemm_kernel(
    const float* __restrict__ adj, const float* __restrict__ graphm,
    const short* __restrict__ XgT, const short* __restrict__ XET,
    float* __restrict__ partials, int ksplit, int kc) {
  const int g = blockIdx.z;
  const float* __restrict__ Am = g ? graphm : adj;
  const short* __restrict__ Xt = g ? XET : XgT;
  const int m0 = blockIdx.x * 128;
  const int split = blockIdx.y;
  const int t = threadIdx.x;
  const int lane = t & 63;
  const int wave = t >> 6;
  const int wr = (wave >> 1) * 64;
  const int wc = (wave & 1) * 64;
  const int fr = lane & 15;
  const int fk = (lane >> 4) * 8;

  __shared__ short As[128][40];   // stride 40 bf16 = 80B: breaks bank aliasing
  __shared__ short Bs[128][40];

  const int ar = t >> 1;
  const int ak = (t & 1) * 16;
  const float* ap = Am + (size_t)(m0 + ar) * NN + ak;
  const short* bp = Xt + (size_t)ar * NN + ak;
  const int kbeg = split * kc;
  const int kend = kbeg + kc;

  // prologue: issue loads for first K-step before anything else
  f4 v0, v1, v2, v3;
  bfrag b0, b1;
  {
    const float* a0 = ap + kbeg;
    v0 = *(const f4*)(a0);
    v1 = *(const f4*)(a0 + 4);
    v2 = *(const f4*)(a0 + 8);
    v3 = *(const f4*)(a0 + 12);
    const short* bq = bp + kbeg;
    b0 = *(const bfrag*)(bq);
    b1 = *(const bfrag*)(bq + 8);
  }

  f4 acc[4][4];
  #pragma unroll
  for (int i = 0; i < 4; i++)
    #pragma unroll
    for (int j = 0; j < 4; j++) acc[i][j] = (f4){0.f, 0.f, 0.f, 0.f};

  #pragma unroll 2
  for (int k0 = kbeg; k0 < kend; k0 += 32) {
    // convert current chunk (this is where the implicit vmcnt lands)
    bfrag h0, h1;
    h0[0] = f2bf(v0[0]); h0[1] = f2bf(v0[1]); h0[2] = f2bf(v0[2]); h0[3] = f2bf(v0[3]);
    h0[4] = f2bf(v1[0]); h0[5] = f2bf(v1[1]); h0[6] = f2bf(v1[2]); h0[7] = f2bf(v1[3]);
    h1[0] = f2bf(v2[0]); h1[1] = f2bf(v2[1]); h1[2] = f2bf(v2[2]); h1[3] = f2bf(v2[3]);
    h1[4] = f2bf(v3[0]); h1[5] = f2bf(v3[1]); h1[6] = f2bf(v3[2]); h1[7] = f2bf(v3[3]);
    *(bfrag*)&As[ar][ak] = h0;
    *(bfrag*)&As[ar][ak + 8] = h1;
    *(bfrag*)&Bs[ar][ak] = b0;
    *(bfrag*)&Bs[ar][ak + 8] = b1;
    __syncthreads();
    // issue next K-step's loads: in flight across MFMA phase + barrier
    if (k0 + 32 < kend) {
      const float* a0 = ap + k0 + 32;
      v0 = *(const f4*)(a0);
      v1 = *(const f4*)(a0 + 4);
      v2 = *(const f4*)(a0 + 8);
      v3 = *(const f4*)(a0 + 12);
      const short* bq = bp + k0 + 32;
      b0 = *(const bfrag*)(bq);
      b1 = *(const bfrag*)(bq + 8);
    }
    bfrag a[4], bb[4];
    #pragma unroll
    for (int i = 0; i < 4; i++) a[i] = *(const bfrag*)&As[wr + i * 16 + fr][fk];
    #pragma unroll
    for (int j = 0; j < 4; j++) bb[j] = *(const bfrag*)&Bs[wc + j * 16 + fr][fk];
    #pragma unroll
    for (int i = 0; i < 4; i++)
      #pragma unroll
      for (int j = 0; j < 4; j++)
        acc[i][j] = __builtin_amdgcn_mfma_f32_16x16x32_bf16(a[i], bb[j], acc[i][j], 0, 0, 0);
    __syncthreads();
  }

  float* outp = partials + (((size_t)g * ksplit + split) * NN + m0) * 128;
  const int crow = (lane >> 4) * 4;
  #pragma unroll
  for (int i = 0; i < 4; i++)
    #pragma unroll
    for (int j = 0; j < 4; j++) {
      float* p = outp + (size_t)(wr + i * 16 + crow) * 128 + wc + j * 16 + fr;
      #pragma unroll
      for (int r = 0; r < 4; r++) p[(size_t)r * 128] = acc[i][j][r];
    }
}

// ---------------- reduce splits + bias + relu -> emb_g (g=0), emb_E (g=1)
__global__ __launch_bounds__(256) void reduce_kernel(
    const float* __restrict__ partials, const float* __restrict__ gcn_b,
    const float* __restrict__ gcnE_b, float* __restrict__ emb_g,
    float* __restrict__ emb_E, int ksplit) {
  int g = blockIdx.y;
  size_t i = ((size_t)blockIdx.x * 256 + threadIdx.x) * 4;
  const float* base = partials + (size_t)g * ksplit * NN * 128;
  f4 s = {0.f, 0.f, 0.f, 0.f};
  for (int sp = 0; sp < ksplit; ++sp)
    s += *(const f4*)(base + (size_t)sp * NN * 128 + i);
  const float* bias = g ? gcnE_b : gcn_b;
  f4 bv = *(const f4*)(bias + (i & 127));
  s += bv;
  s[0] = fmaxf(s[0], 0.f); s[1] = fmaxf(s[1], 0.f);
  s[2] = fmaxf(s[2], 0.f); s[3] = fmaxf(s[3], 0.f);
  float* outp = g ? emb_E : emb_g;
  *(f4*)(outp + i) = s;
}

// ---------------- fused attention + concat + final matmul ----------------
__global__ __launch_bounds__(128) void attn_kernel(
    const int* __restrict__ node_rd, const int* __restrict__ batch_node_idx,
    const float* __restrict__ Qa, const float* __restrict__ Ka,
    const float* __restrict__ Va, const float* __restrict__ tfn,
    const float* __restrict__ emb_g, const float* __restrict__ simi,
    const float* __restrict__ lin_W, const float* __restrict__ lin_b,
    float* __restrict__ outr) {
  int b = blockIdx.x;
  int t = threadIdx.x;
  __shared__ int idx[CTX1];
  __shared__ float tf0[64];
  __shared__ float qv[128];
  __shared__ float cosv[CTX1];
  __shared__ float sc[8][CTX1];
  __shared__ float femb[384];

  if (t < CTX1) idx[t] = node_rd[(size_t)b * CTX1 + t] + (t == 0 ? SRC : 0);
  __syncthreads();
  int i0 = idx[0];
  if (t < 64) tf0[t] = tfn[(size_t)i0 * 64 + t];
  qv[t] = Qa[(size_t)i0 * 128 + t];
  __syncthreads();

  {  // cos[c]: 4 lanes per context
    int c = t >> 2, q = t & 3;
    const float* tfc = tfn + (size_t)idx[c] * 64;
    float s = 0.f;
    #pragma unroll
    for (int j = 0; j < 16; j++) s += tf0[q + j * 4] * tfc[q + j * 4];
    s += __shfl_xor(s, 1);
    s += __shfl_xor(s, 2);
    if (q == 0) cosv[c] = s;
  }
  __syncthreads();

  // scores[h][c]
  for (int p = t; p < 256; p += 128) {
    int h = p >> 5, c = p & 31;
    const float* kp = Ka + (size_t)idx[c] * 128 + h * 16;
    float s = 0.f;
    #pragma unroll
    for (int d = 0; d < 16; d++) s += qv[h * 16 + d] * kp[d];
    sc[h][c] = s * 0.25f + cosv[c];
  }
  __syncthreads();

  {  // softmax over c, 16 lanes per head
    int h = t >> 4, l = t & 15;
    float s0 = sc[h][l], s1 = sc[h][l + 16];
    float m = fmaxf(s0, s1);
    #pragma unroll
    for (int o = 1; o < 16; o <<= 1) m = fmaxf(m, __shfl_xor(m, o));
    float e0 = expf(s0 - m), e1 = expf(s1 - m);
    float sum = e0 + e1;
    #pragma unroll
    for (int o = 1; o < 16; o <<= 1) sum += __shfl_xor(sum, o);
    float inv = 1.0f / sum;
    sc[h][l] = e0 * inv;
    sc[h][l + 16] = e1 * inv;
  }
  __syncthreads();

  {  // PV + elu
    int h = t >> 4, d = t & 15;
    float o = 0.f;
    #pragma unroll 4
    for (int c = 0; c < CTX1; c++)
      o += sc[h][c] * Va[(size_t)idx[c] * 128 + h * 16 + d];
    femb[128 + t] = (o > 0.f) ? o : expm1f(o);
  }
  int bn = batch_node_idx[b];
  femb[t] = emb_g[(size_t)bn * 128 + t];
  femb[256 + t] = simi[(size_t)b * 128 + t];
  __syncthreads();

  float accv = lin_b[t];
  #pragma unroll 8
  for (int j = 0; j < 384; j++) accv = fmaf(femb[j], lin_W[(size_t)j * 128 + t], accv);
  outr[(size_t)b * 128 + t] = accv;
}

// ---------------- loss ----------------
__global__ __launch_bounds__(256) void loss_kernel(
    const float* __restrict__ target, const float* __restrict__ result,
    float* __restrict__ out_loss) {
  int t = threadIdx.x;
  float s = 0.f;
  for (int b = t; b < BSZ; b += 256) {
    float d = target[(size_t)b * 128 + DROPC] - result[(size_t)b * 128 + DROPC];
    s += d * d;
  }
  #pragma unroll
  for (int o = 32; o > 0; o >>= 1) s += __shfl_xor(s, o);
  __shared__ float red[4];
  if ((t & 63) == 0) red[t >> 6] = s;
  __syncthreads();
  if (t == 0) out_loss[0] = (red[0] + red[1] + red[2] + red[3]) * (1.0f / BSZ);
}

extern "C" void kernel_launch(void* const* d_in, const int* in_sizes, int n_in,
                              void* d_out, int out_size, void* d_ws, size_t ws_size,
                              hipStream_t stream) {
  const float* adj = (const float*)d_in[0];
  const float* graphm = (const float*)d_in[1];
  const float* node_emb_gcn = (const float*)d_in[2];
  const float* trainfeature = (const float*)d_in[3];
  const float* target_emb = (const float*)d_in[4];
  const float* bsnf = (const float*)d_in[5];
  const int* batch_node_idx = (const int*)d_in[8];
  const int* node_rd = (const int*)d_in[9];
  const float* translate_W = (const float*)d_in[10];
  const float* translate_b = (const float*)d_in[11];
  const float* paraForCos = (const float*)d_in[12];
  const float* gcn_W = (const float*)d_in[13];
  const float* gcn_b = (const float*)d_in[14];
  const float* gcnE_W = (const float*)d_in[15];
  const float* gcnE_b = (const float*)d_in[16];
  const float* Wq = (const float*)d_in[17];
  const float* Wk = (const float*)d_in[18];
  const float* Wv = (const float*)d_in[19];
  const float* lin_W = (const float*)d_in[20];
  const float* lin_b = (const float*)d_in[21];

  char* ws = (char*)d_ws;
  size_t off = 0;
  auto alloc = [&](size_t bytes) {
    void* p = ws + off;
    off += (bytes + 255) & ~(size_t)255;
    return p;
  };
  short* XgT = (short*)alloc((size_t)128 * NN * 2);
  short* XET = (short*)alloc((size_t)128 * NN * 2);
  float* tfn = (float*)alloc((size_t)NN * 64 * 4);
  float* wsum = (float*)alloc((size_t)BSZ * 128 * 4);
  float* simi = (float*)alloc((size_t)BSZ * 128 * 4);
  float* Qa = (float*)alloc((size_t)NN * 128 * 4);
  float* Ka = (float*)alloc((size_t)NN * 128 * 4);
  float* Va = (float*)alloc((size_t)NN * 128 * 4);
  float* emb_g = (float*)alloc((size_t)NN * 128 * 4);
  float* emb_E = (float*)alloc((size_t)NN * 128 * 4);
  float* meanpara = (float*)alloc(256);

  size_t per_split = 2ull * NN * 128 * 4;  // both gemms, one split = 8MB
  int ksplit = 1;
  if (off + 8 * per_split <= ws_size) ksplit = 8;
  else if (off + 4 * per_split <= ws_size) ksplit = 4;
  else if (off + 2 * per_split <= ws_size) ksplit = 2;
  float* partials = (float*)(ws + off);
  int kc = NN / ksplit;

  float* out_res = (float*)d_out;
  float* out_loss = out_res + (size_t)BSZ * 128;

  prep_kernel<<<4097, 256, 0, stream>>>(trainfeature, bsnf, paraForCos, tfn, wsum, meanpara);
  proj2_kernel<<<dim3(NN / 64, 2), 256, 0, stream>>>(node_emb_gcn, gcn_W, XgT,
                                                     trainfeature, gcnE_W, XET);
  big_gemm_kernel<<<dim3(NN / 128, ksplit, 2), 256, 0, stream>>>(adj, graphm, XgT, XET,
                                                                 partials, ksplit, kc);
  reduce_kernel<<<dim3(NN * 128 / (256 * 4), 2), 256, 0, stream>>>(partials, gcn_b, gcnE_b,
                                                                   emb_g, emb_E, ksplit);
  qkv_kernel<<<dim3(NN / 64, 3), 256, 0, stream>>>(emb_E, Wq, Wk, Wv, Qa, Ka, Va);
  gemm128_kernel<<<BSZ / 64, 256, 0, stream>>>(wsum, translate_W, translate_b, meanpara,
                                               simi, nullptr, BSZ);
  attn_kernel<<<BSZ, 128, 0, stream>>>(node_rd, batch_node_idx, Qa, Ka, Va, tfn, emb_g,
                                       simi, lin_W, lin_b, out_res);
  loss_kernel<<<1, 256, 0, stream>>>(target_emb, out_res, out_loss);
}

// Round 3
// 309.637 us; speedup vs baseline: 1.2229x; 1.0757x over previous
//
#include <hip/hip_runtime.h>
#include <hip/hip_bf16.h>

#define NN 8192
#define ND 128
#define BSZ 4096
#define CTX1 32
#define SRC 4096
#define TOPK 8
#define DROPC 5

using f4 = __attribute__((ext_vector_type(4))) float;
using bfrag = __attribute__((ext_vector_type(8))) short;

__device__ __forceinline__ short f2bf(float x) {
  __hip_bfloat16 h = __float2bfloat16(x);
  return __builtin_bit_cast(short, h);
}

// ---------------- prep: tfn (normalized trainfeature[:, :64]), wsum, meanpara ----
__global__ __launch_bounds__(256) void prep_kernel(
    const float* __restrict__ trainfeature, const float* __restrict__ bsnf,
    const float* __restrict__ para, float* __restrict__ tfn,
    float* __restrict__ wsum, float* __restrict__ meanpara) {
  int blk = blockIdx.x;
  int t = threadIdx.x;
  if (blk < 2048) {                      // tfn: 4 rows per block, one wave per row
    int row = blk * 4 + (t >> 6);
    int j = t & 63;
    float x = trainfeature[(size_t)row * ND + j];
    float ss = x * x;
    #pragma unroll
    for (int o = 32; o > 0; o >>= 1) ss += __shfl_xor(ss, o);
    float nrm = sqrtf(ss) + 1e-8f;
    tfn[(size_t)row * 64 + j] = x / nrm;
  } else if (blk < 4096) {               // wsum: 2 rows per block
    int b = (blk - 2048) * 2 + (t >> 7);
    int k = t & 127;
    float s = 0.f;
    #pragma unroll
    for (int tt = 0; tt < TOPK; ++tt)
      s += para[tt] * bsnf[((size_t)b * TOPK + tt) * ND + k];
    wsum[(size_t)b * ND + k] = s * (1.0f / TOPK);
  } else {
    if (t == 0) {
      float s = 0.f;
      for (int tt = 0; tt < TOPK; ++tt) s += para[tt];
      *meanpara = s * (1.0f / TOPK);
    }
  }
}

// ---------------- generic f32 GEMM body: C[M][128] = A[M][128] @ W[128][128]
// Optional f32 output Cf. Optional bf16 MFMA-fragment-packed output Xpack:
// frag (kt,nt) is 64 lanes x 8 shorts contiguous (1KB); lane l, elem j holds
// X[kt*32 + (l>>4)*8 + j][nt*16 + (l&15)].
__device__ __forceinline__ void gemm128_body(
    const float* __restrict__ A, const float* __restrict__ W,
    const float* __restrict__ bias, const float* __restrict__ bscale_ptr,
    float* __restrict__ Cf, short* __restrict__ Xpack, int row0) {
  __shared__ float Ws[128][132];
  __shared__ float As[64][128];
  int t = threadIdx.x;
  for (int i = t; i < 128 * 32; i += 256) {
    int r = i >> 5, c = (i & 31) * 4;
    *(f4*)&Ws[r][c] = *(const f4*)&W[(size_t)r * 128 + c];
  }
  for (int i = t; i < 64 * 32; i += 256) {
    int r = i >> 5, c = (i & 31) * 4;
    *(f4*)&As[r][c] = *(const f4*)&A[(size_t)(row0 + r) * 128 + c];
  }
  __syncthreads();
  int tr = (t >> 5) * 8;
  int tc = (t & 31) * 4;
  float acc[8][4];
  #pragma unroll
  for (int i = 0; i < 8; i++)
    #pragma unroll
    for (int j = 0; j < 4; j++) acc[i][j] = 0.f;
  for (int k = 0; k < 128; k++) {
    f4 w = *(const f4*)&Ws[k][tc];
    #pragma unroll
    for (int i = 0; i < 8; i++) {
      float a = As[tr + i][k];
      acc[i][0] = fmaf(a, w[0], acc[i][0]);
      acc[i][1] = fmaf(a, w[1], acc[i][1]);
      acc[i][2] = fmaf(a, w[2], acc[i][2]);
      acc[i][3] = fmaf(a, w[3], acc[i][3]);
    }
  }
  if (bias) {
    float bsc = bscale_ptr ? *bscale_ptr : 1.0f;
    #pragma unroll
    for (int i = 0; i < 8; i++)
      #pragma unroll
      for (int j = 0; j < 4; j++) acc[i][j] += bias[tc + j] * bsc;
  }
  if (Cf) {
    #pragma unroll
    for (int i = 0; i < 8; i++) {
      int r = row0 + tr + i;
      #pragma unroll
      for (int j = 0; j < 4; j++) Cf[(size_t)r * 128 + tc + j] = acc[i][j];
    }
  }
  if (Xpack) {
    int kb = row0 + tr;              // multiple of 8
    int kt = kb >> 5;
    int lane_hi = (kb >> 3) & 3;
    #pragma unroll
    for (int j = 0; j < 4; j++) {
      int n = tc + j;
      int ln = (n & 15) | (lane_hi << 4);
      bfrag h;
      #pragma unroll
      for (int i = 0; i < 8; i++) h[i] = f2bf(acc[i][j]);
      *(bfrag*)&Xpack[((size_t)(kt * 8 + (n >> 4)) * 64 + ln) * 8] = h;
    }
  }
}

__global__ __launch_bounds__(256) void gemm128_kernel(
    const float* __restrict__ A, const float* __restrict__ W,
    const float* __restrict__ bias, const float* __restrict__ bscale_ptr,
    float* __restrict__ Cf, short* __restrict__ Xpack) {
  gemm128_body(A, W, bias, bscale_ptr, Cf, Xpack, blockIdx.x * 64);
}

// 2 projections in one launch, writing MFMA-packed bf16
__global__ __launch_bounds__(256) void proj2_kernel(
    const float* __restrict__ A0, const float* __restrict__ W0, short* __restrict__ T0,
    const float* __restrict__ A1, const float* __restrict__ W1, short* __restrict__ T1) {
  if (blockIdx.y == 0)
    gemm128_body(A0, W0, nullptr, nullptr, nullptr, T0, blockIdx.x * 64);
  else
    gemm128_body(A1, W1, nullptr, nullptr, nullptr, T1, blockIdx.x * 64);
}

// QKV in one launch
__global__ __launch_bounds__(256) void qkv_kernel(
    const float* __restrict__ A, const float* __restrict__ Wq,
    const float* __restrict__ Wk, const float* __restrict__ Wv,
    float* __restrict__ Qa, float* __restrict__ Ka, float* __restrict__ Va) {
  const float* W = blockIdx.y == 0 ? Wq : (blockIdx.y == 1 ? Wk : Wv);
  float* C = blockIdx.y == 0 ? Qa : (blockIdx.y == 1 ? Ka : Va);
  gemm128_body(A, W, nullptr, nullptr, C, nullptr, blockIdx.x * 64);
}

// ---------------- big GEMM: partial[g][split] = A_f32(8192x8192) @ X_bf16(8192x128)
// No LDS, no barriers: each wave owns a 32x128 output tile, loads A fragments
// directly global->reg (16x128B full lines), converts in-register, B from the
// L2-resident packed X. Explicit 2-set software pipeline, free-running waves.
struct Step {
  f4 a00, a01, a10, a11;   // A rows r0 (frags 0) and r0+16 (frags 1)
  bfrag b0, b1, b2, b3, b4, b5, b6, b7;
};

__global__ __launch_bounds__(256, 2) void big_gemm_kernel(
    const float* __restrict__ adj, const float* __restrict__ graphm,
    const short* __restrict__ XgP, const short* __restrict__ XEP,
    float* __restrict__ partials, int ksplit, int kc) {
  const int g = blockIdx.z;
  const float* __restrict__ Am = g ? graphm : adj;
  const short* __restrict__ Xp = g ? XEP : XgP;
  const int m0 = blockIdx.x * 128;
  const int t = threadIdx.x;
  const int lane = t & 63;
  const int w = t >> 6;

  const int r0 = m0 + w * 32 + (lane & 15);
  const int koff = (lane >> 4) * 8;
  const float* Ap0 = Am + (size_t)r0 * NN + koff;
  const float* Ap1 = Ap0 + (size_t)16 * NN;
  const short* Xb = Xp + (size_t)lane * 8;

  const int kbeg = blockIdx.y * kc;
  const int kend = kbeg + kc;

  Step s0, s1;
  auto load = [&](Step& s, int k0) {
    const float* pa = Ap0 + k0;
    s.a00 = *(const f4*)(pa);
    s.a01 = *(const f4*)(pa + 4);
    const float* pb = Ap1 + k0;
    s.a10 = *(const f4*)(pb);
    s.a11 = *(const f4*)(pb + 4);
    const short* xq = Xb + (size_t)(k0 >> 5) * 4096;
    s.b0 = *(const bfrag*)(xq);
    s.b1 = *(const bfrag*)(xq + 512);
    s.b2 = *(const bfrag*)(xq + 1024);
    s.b3 = *(const bfrag*)(xq + 1536);
    s.b4 = *(const bfrag*)(xq + 2048);
    s.b5 = *(const bfrag*)(xq + 2560);
    s.b6 = *(const bfrag*)(xq + 3072);
    s.b7 = *(const bfrag*)(xq + 3584);
  };

  f4 acc0[8], acc1[8];
  #pragma unroll
  for (int i = 0; i < 8; i++) {
    acc0[i] = (f4){0.f, 0.f, 0.f, 0.f};
    acc1[i] = (f4){0.f, 0.f, 0.f, 0.f};
  }

  auto compute = [&](Step& s) {
    bfrag af0, af1;
    af0[0] = f2bf(s.a00[0]); af0[1] = f2bf(s.a00[1]);
    af0[2] = f2bf(s.a00[2]); af0[3] = f2bf(s.a00[3]);
    af0[4] = f2bf(s.a01[0]); af0[5] = f2bf(s.a01[1]);
    af0[6] = f2bf(s.a01[2]); af0[7] = f2bf(s.a01[3]);
    af1[0] = f2bf(s.a10[0]); af1[1] = f2bf(s.a10[1]);
    af1[2] = f2bf(s.a10[2]); af1[3] = f2bf(s.a10[3]);
    af1[4] = f2bf(s.a11[0]); af1[5] = f2bf(s.a11[1]);
    af1[6] = f2bf(s.a11[2]); af1[7] = f2bf(s.a11[3]);
    acc0[0] = __builtin_amdgcn_mfma_f32_16x16x32_bf16(af0, s.b0, acc0[0], 0, 0, 0);
    acc1[0] = __builtin_amdgcn_mfma_f32_16x16x32_bf16(af1, s.b0, acc1[0], 0, 0, 0);
    acc0[1] = __builtin_amdgcn_mfma_f32_16x16x32_bf16(af0, s.b1, acc0[1], 0, 0, 0);
    acc1[1] = __builtin_amdgcn_mfma_f32_16x16x32_bf16(af1, s.b1, acc1[1], 0, 0, 0);
    acc0[2] = __builtin_amdgcn_mfma_f32_16x16x32_bf16(af0, s.b2, acc0[2], 0, 0, 0);
    acc1[2] = __builtin_amdgcn_mfma_f32_16x16x32_bf16(af1, s.b2, acc1[2], 0, 0, 0);
    acc0[3] = __builtin_amdgcn_mfma_f32_16x16x32_bf16(af0, s.b3, acc0[3], 0, 0, 0);
    acc1[3] = __builtin_amdgcn_mfma_f32_16x16x32_bf16(af1, s.b3, acc1[3], 0, 0, 0);
    acc0[4] = __builtin_amdgcn_mfma_f32_16x16x32_bf16(af0, s.b4, acc0[4], 0, 0, 0);
    acc1[4] = __builtin_amdgcn_mfma_f32_16x16x32_bf16(af1, s.b4, acc1[4], 0, 0, 0);
    acc0[5] = __builtin_amdgcn_mfma_f32_16x16x32_bf16(af0, s.b5, acc0[5], 0, 0, 0);
    acc1[5] = __builtin_amdgcn_mfma_f32_16x16x32_bf16(af1, s.b5, acc1[5], 0, 0, 0);
    acc0[6] = __builtin_amdgcn_mfma_f32_16x16x32_bf16(af0, s.b6, acc0[6], 0, 0, 0);
    acc1[6] = __builtin_amdgcn_mfma_f32_16x16x32_bf16(af1, s.b6, acc1[6], 0, 0, 0);
    acc0[7] = __builtin_amdgcn_mfma_f32_16x16x32_bf16(af0, s.b7, acc0[7], 0, 0, 0);
    acc1[7] = __builtin_amdgcn_mfma_f32_16x16x32_bf16(af1, s.b7, acc1[7], 0, 0, 0);
  };

  load(s0, kbeg);
  load(s1, kbeg + 32);
  for (int k0 = kbeg; k0 < kend; k0 += 64) {
    compute(s0);
    if (k0 + 64 < kend) load(s0, k0 + 64);
    compute(s1);
    if (k0 + 96 < kend) load(s1, k0 + 96);
  }

  float* outp = partials + (((size_t)g * ksplit + blockIdx.y) * NN + m0) * 128;
  const int crow = (lane >> 4) * 4;
  const int ccol = lane & 15;
  #pragma unroll
  for (int nt = 0; nt < 8; nt++) {
    #pragma unroll
    for (int r = 0; r < 4; r++) {
      outp[(size_t)(w * 32 + crow + r) * 128 + nt * 16 + ccol] = acc0[nt][r];
      outp[(size_t)(w * 32 + 16 + crow + r) * 128 + nt * 16 + ccol] = acc1[nt][r];
    }
  }
}

// ---------------- reduce splits + bias + relu -> emb_g (g=0), emb_E (g=1)
__global__ __launch_bounds__(256) void reduce_kernel(
    const float* __restrict__ partials, const float* __restrict__ gcn_b,
    const float* __restrict__ gcnE_b, float* __restrict__ emb_g,
    float* __restrict__ emb_E, int ksplit) {
  int g = blockIdx.y;
  size_t i = ((size_t)blockIdx.x * 256 + threadIdx.x) * 4;
  const float* base = partials + (size_t)g * ksplit * NN * 128;
  f4 s = {0.f, 0.f, 0.f, 0.f};
  for (int sp = 0; sp < ksplit; ++sp)
    s += *(const f4*)(base + (size_t)sp * NN * 128 + i);
  const float* bias = g ? gcnE_b : gcn_b;
  f4 bv = *(const f4*)(bias + (i & 127));
  s += bv;
  s[0] = fmaxf(s[0], 0.f); s[1] = fmaxf(s[1], 0.f);
  s[2] = fmaxf(s[2], 0.f); s[3] = fmaxf(s[3], 0.f);
  float* outp = g ? emb_E : emb_g;
  *(f4*)(outp + i) = s;
}

// ---------------- fused attention + concat + final matmul ----------------
__global__ __launch_bounds__(128) void attn_kernel(
    const int* __restrict__ node_rd, const int* __restrict__ batch_node_idx,
    const float* __restrict__ Qa, const float* __restrict__ Ka,
    const float* __restrict__ Va, const float* __restrict__ tfn,
    const float* __restrict__ emb_g, const float* __restrict__ simi,
    const float* __restrict__ lin_W, const float* __restrict__ lin_b,
    float* __restrict__ outr) {
  int b = blockIdx.x;
  int t = threadIdx.x;
  __shared__ int idx[CTX1];
  __shared__ float tf0[64];
  __shared__ float qv[128];
  __shared__ float cosv[CTX1];
  __shared__ float sc[8][CTX1];
  __shared__ float femb[384];

  if (t < CTX1) idx[t] = node_rd[(size_t)b * CTX1 + t] + (t == 0 ? SRC : 0);
  __syncthreads();
  int i0 = idx[0];
  if (t < 64) tf0[t] = tfn[(size_t)i0 * 64 + t];
  qv[t] = Qa[(size_t)i0 * 128 + t];
  __syncthreads();

  {  // cos[c]: 4 lanes per context
    int c = t >> 2, q = t & 3;
    const float* tfc = tfn + (size_t)idx[c] * 64;
    float s = 0.f;
    #pragma unroll
    for (int j = 0; j < 16; j++) s += tf0[q + j * 4] * tfc[q + j * 4];
    s += __shfl_xor(s, 1);
    s += __shfl_xor(s, 2);
    if (q == 0) cosv[c] = s;
  }
  __syncthreads();

  // scores[h][c]
  for (int p = t; p < 256; p += 128) {
    int h = p >> 5, c = p & 31;
    const float* kp = Ka + (size_t)idx[c] * 128 + h * 16;
    float s = 0.f;
    #pragma unroll
    for (int d = 0; d < 16; d++) s += qv[h * 16 + d] * kp[d];
    sc[h][c] = s * 0.25f + cosv[c];
  }
  __syncthreads();

  {  // softmax over c, 16 lanes per head
    int h = t >> 4, l = t & 15;
    float s0 = sc[h][l], s1 = sc[h][l + 16];
    float m = fmaxf(s0, s1);
    #pragma unroll
    for (int o = 1; o < 16; o <<= 1) m = fmaxf(m, __shfl_xor(m, o));
    float e0 = expf(s0 - m), e1 = expf(s1 - m);
    float sum = e0 + e1;
    #pragma unroll
    for (int o = 1; o < 16; o <<= 1) sum += __shfl_xor(sum, o);
    float inv = 1.0f / sum;
    sc[h][l] = e0 * inv;
    sc[h][l + 16] = e1 * inv;
  }
  __syncthreads();

  {  // PV + elu
    int h = t >> 4, d = t & 15;
    float o = 0.f;
    #pragma unroll 4
    for (int c = 0; c < CTX1; c++)
      o += sc[h][c] * Va[(size_t)idx[c] * 128 + h * 16 + d];
    femb[128 + t] = (o > 0.f) ? o : expm1f(o);
  }
  int bn = batch_node_idx[b];
  femb[t] = emb_g[(size_t)bn * 128 + t];
  femb[256 + t] = simi[(size_t)b * 128 + t];
  __syncthreads();

  float accv = lin_b[t];
  #pragma unroll 8
  for (int j = 0; j < 384; j++) accv = fmaf(femb[j], lin_W[(size_t)j * 128 + t], accv);
  outr[(size_t)b * 128 + t] = accv;
}

// ---------------- loss ----------------
__global__ __launch_bounds__(256) void loss_kernel(
    const float* __restrict__ target, const float* __restrict__ result,
    float* __restrict__ out_loss) {
  int t = threadIdx.x;
  float s = 0.f;
  for (int b = t; b < BSZ; b += 256) {
    float d = target[(size_t)b * 128 + DROPC] - result[(size_t)b * 128 + DROPC];
    s += d * d;
  }
  #pragma unroll
  for (int o = 32; o > 0; o >>= 1) s += __shfl_xor(s, o);
  __shared__ float red[4];
  if ((t & 63) == 0) red[t >> 6] = s;
  __syncthreads();
  if (t == 0) out_loss[0] = (red[0] + red[1] + red[2] + red[3]) * (1.0f / BSZ);
}

extern "C" void kernel_launch(void* const* d_in, const int* in_sizes, int n_in,
                              void* d_out, int out_size, void* d_ws, size_t ws_size,
                              hipStream_t stream) {
  const float* adj = (const float*)d_in[0];
  const float* graphm = (const float*)d_in[1];
  const float* node_emb_gcn = (const float*)d_in[2];
  const float* trainfeature = (const float*)d_in[3];
  const float* target_emb = (const float*)d_in[4];
  const float* bsnf = (const float*)d_in[5];
  const int* batch_node_idx = (const int*)d_in[8];
  const int* node_rd = (const int*)d_in[9];
  const float* translate_W = (const float*)d_in[10];
  const float* translate_b = (const float*)d_in[11];
  const float* paraForCos = (const float*)d_in[12];
  const float* gcn_W = (const float*)d_in[13];
  const float* gcn_b = (const float*)d_in[14];
  const float* gcnE_W = (const float*)d_in[15];
  const float* gcnE_b = (const float*)d_in[16];
  const float* Wq = (const float*)d_in[17];
  const float* Wk = (const float*)d_in[18];
  const float* Wv = (const float*)d_in[19];
  const float* lin_W = (const float*)d_in[20];
  const float* lin_b = (const float*)d_in[21];

  char* ws = (char*)d_ws;
  size_t off = 0;
  auto alloc = [&](size_t bytes) {
    void* p = ws + off;
    off += (bytes + 255) & ~(size_t)255;
    return p;
  };
  short* XgP = (short*)alloc((size_t)128 * NN * 2);
  short* XEP = (short*)alloc((size_t)128 * NN * 2);
  float* tfn = (float*)alloc((size_t)NN * 64 * 4);
  float* wsum = (float*)alloc((size_t)BSZ * 128 * 4);
  float* simi = (float*)alloc((size_t)BSZ * 128 * 4);
  float* Qa = (float*)alloc((size_t)NN * 128 * 4);
  float* Ka = (float*)alloc((size_t)NN * 128 * 4);
  float* Va = (float*)alloc((size_t)NN * 128 * 4);
  float* emb_g = (float*)alloc((size_t)NN * 128 * 4);
  float* emb_E = (float*)alloc((size_t)NN * 128 * 4);
  float* meanpara = (float*)alloc(256);

  size_t per_split = 2ull * NN * 128 * 4;  // both gemms, one split = 8MB
  int ksplit = 1;
  if (off + 4 * per_split <= ws_size) ksplit = 4;
  else if (off + 2 * per_split <= ws_size) ksplit = 2;
  float* partials = (float*)(ws + off);
  int kc = NN / ksplit;

  float* out_res = (float*)d_out;
  float* out_loss = out_res + (size_t)BSZ * 128;

  prep_kernel<<<4097, 256, 0, stream>>>(trainfeature, bsnf, paraForCos, tfn, wsum, meanpara);
  proj2_kernel<<<dim3(NN / 64, 2), 256, 0, stream>>>(node_emb_gcn, gcn_W, XgP,
                                                     trainfeature, gcnE_W, XEP);
  big_gemm_kernel<<<dim3(NN / 128, ksplit, 2), 256, 0, stream>>>(adj, graphm, XgP, XEP,
                                                                 partials, ksplit, kc);
  reduce_kernel<<<dim3(NN * 128 / (256 * 4), 2), 256, 0, stream>>>(partials, gcn_b, gcnE_b,
                                                                   emb_g, emb_E, ksplit);
  qkv_kernel<<<dim3(NN / 64, 3), 256, 0, stream>>>(emb_E, Wq, Wk, Wv, Qa, Ka, Va);
  gemm128_kernel<<<BSZ / 64, 256, 0, stream>>>(wsum, translate_W, translate_b, meanpara,
                                               simi, nullptr);
  attn_kernel<<<BSZ, 128, 0, stream>>>(node_rd, batch_node_idx, Qa, Ka, Va, tfn, emb_g,
                                       simi, lin_W, lin_b, out_res);
  loss_kernel<<<1, 256, 0, stream>>>(target_emb, out_res, out_loss);
}